// Round 6
// baseline (58.736 us; speedup 1.0000x reference)
//
#include <hip/hip_runtime.h>
#include <math.h>

#define T_TOTAL 8192
#define D_TOTAL 4096
#define E 64
#define TOPK 8
#define NKB (D_TOTAL / 32)     // 128 k-blocks of 32

typedef short short8 __attribute__((ext_vector_type(8)));
typedef float f32x4 __attribute__((ext_vector_type(4)));

// scalar split (prep kernel only)
__device__ __forceinline__ void split3(const float* v8, short8& h, short8& m, short8& l) {
#pragma unroll
    for (int j = 0; j < 8; ++j) {
        const float f = v8[j];
        const unsigned u = __float_as_uint(f);
        const unsigned hu = u & 0xffff0000u;
        const float r1 = f - __uint_as_float(hu);
        const unsigned mu = __float_as_uint(r1) & 0xffff0000u;
        const float r2 = r1 - __uint_as_float(mu);
        const unsigned lu = __float_as_uint(r2);
        h[j] = (short)(hu >> 16);
        m[j] = (short)(mu >> 16);
        l[j] = (short)(lu >> 16);
    }
}

// v_perm-based split: pack 2 bf16 per op. h/m/l as 4 packed uints each.
__device__ __forceinline__ void split3v(const float* v, short8& h, short8& m, short8& l) {
    unsigned* hp = reinterpret_cast<unsigned*>(&h);
    unsigned* mp = reinterpret_cast<unsigned*>(&m);
    unsigned* lp = reinterpret_cast<unsigned*>(&l);
#pragma unroll
    for (int p = 0; p < 4; ++p) {
        const float a = v[2 * p], b = v[2 * p + 1];
        // [b.hi16 | a.hi16]
        const unsigned hw = __builtin_amdgcn_perm(__float_as_uint(b), __float_as_uint(a), 0x07060302u);
        const float r0 = a - __uint_as_float(hw << 16);
        const float r1 = b - __uint_as_float(hw & 0xffff0000u);
        const unsigned mw = __builtin_amdgcn_perm(__float_as_uint(r1), __float_as_uint(r0), 0x07060302u);
        const float s0 = r0 - __uint_as_float(mw << 16);
        const float s1 = r1 - __uint_as_float(mw & 0xffff0000u);
        const unsigned lw = __builtin_amdgcn_perm(__float_as_uint(s1), __float_as_uint(s0), 0x07060302u);
        hp[p] = hw; mp[p] = mw; lp[p] = lw;
    }
}

// ---------------- Prep: w -> frag-ordered bf16 split arrays ----------------
__global__ __launch_bounds__(256)
void prep_w(const float* __restrict__ w, short8* __restrict__ Bh,
            short8* __restrict__ Bm, short8* __restrict__ Bl) {
    const int t = blockIdx.x * 256 + threadIdx.x;   // [0, NKB*4*64)
    const int lane = t & 63;
    const int nt = (t >> 6) & 3;
    const int kb = t >> 8;
    const int e = nt * 16 + (lane & 15);
    const int k = kb * 32 + (lane >> 4) * 8;

    const float* src = w + (size_t)e * D_TOTAL + k;
    float v[8];
    *reinterpret_cast<float4*>(&v[0]) = *reinterpret_cast<const float4*>(src);
    *reinterpret_cast<float4*>(&v[4]) = *reinterpret_cast<const float4*>(src + 4);

    short8 h, m, l;
    split3(v, h, m, l);
    Bh[t] = h; Bm[t] = m; Bl[t] = l;
}

// ---------------- Fused: M=16 tokens/block, 16 waves, wave K-chunk = 256 ----
// 512 blocks -> 2 blocks/CU -> 8 waves/SIMD. Lean VGPR (<=64 target).
__global__ __launch_bounds__(1024, 8)
void fused_router(const float* __restrict__ x,
                  const short8* __restrict__ Bh, const short8* __restrict__ Bm,
                  const short8* __restrict__ Bl,
                  float* __restrict__ out) {
    __shared__ float tiles[8 * 1024];   // 32 KB
    __shared__ float fin[1024];         // 4 KB: logits [t][e]

    const int tid = threadIdx.x;
    const int lane = tid & 63;
    const int wv = tid >> 6;
    const int tok0 = blockIdx.x * 16;

    const int row = lane & 15;
    const int kq = lane >> 4;

    const float* xb = x + (size_t)(tok0 + row) * D_TOTAL + kq * 8;

    f32x4 acc[4];
#pragma unroll
    for (int n = 0; n < 4; ++n) acc[n] = (f32x4){0.f, 0.f, 0.f, 0.f};

    const int kbase = wv * 256;

    float xr[8];
    {
        const float* ap = xb + kbase;
        *reinterpret_cast<float4*>(&xr[0]) = *reinterpret_cast<const float4*>(ap);
        *reinterpret_cast<float4*>(&xr[4]) = *reinterpret_cast<const float4*>(ap + 4);
    }

#pragma unroll
    for (int kb = 0; kb < 8; ++kb) {
        const int k = kbase + kb * 32;
        const int gkb = k >> 5;

        // split current x fragment, then immediately issue next kb's x load
        short8 ah, am_, al;
        split3v(xr, ah, am_, al);
        if (kb < 7) {
            const float* ap = xb + k + 32;
            *reinterpret_cast<float4*>(&xr[0]) = *reinterpret_cast<const float4*>(ap);
            *reinterpret_cast<float4*>(&xr[4]) = *reinterpret_cast<const float4*>(ap + 4);
        }

#pragma unroll
        for (int nt = 0; nt < 4; ++nt) {
            const size_t bi = (size_t)(gkb * 4 + nt) * 64 + lane;
            const short8 bh = Bh[bi];
            const short8 bm = Bm[bi];
            const short8 bl = Bl[bi];
            f32x4 c = acc[nt];
            c = __builtin_amdgcn_mfma_f32_16x16x32_bf16(ah,  bh, c, 0, 0, 0);
            c = __builtin_amdgcn_mfma_f32_16x16x32_bf16(ah,  bm, c, 0, 0, 0);
            c = __builtin_amdgcn_mfma_f32_16x16x32_bf16(am_, bh, c, 0, 0, 0);
            c = __builtin_amdgcn_mfma_f32_16x16x32_bf16(am_, bm, c, 0, 0, 0);
            c = __builtin_amdgcn_mfma_f32_16x16x32_bf16(ah,  bl, c, 0, 0, 0);
            c = __builtin_amdgcn_mfma_f32_16x16x32_bf16(al,  bh, c, 0, 0, 0);
            acc[nt] = c;
        }
    }

    // ---- reduce 16 wave-partials: fold 16->8 in LDS, then flat 8-way sum ----
    if (wv >= 8) {
        float* s = &tiles[(size_t)(wv - 8) * 1024 + lane];
#pragma unroll
        for (int nt = 0; nt < 4; ++nt)
#pragma unroll
            for (int r = 0; r < 4; ++r)
                s[(nt * 4 + r) * 64] = acc[nt][r];
    }
    __syncthreads();
    if (wv < 8) {
        float* s = &tiles[(size_t)wv * 1024 + lane];
#pragma unroll
        for (int nt = 0; nt < 4; ++nt)
#pragma unroll
            for (int r = 0; r < 4; ++r) {
                const int j = (nt * 4 + r) * 64;
                s[j] = acc[nt][r] + s[j];
            }
    }
    __syncthreads();

    // flat sum over 8 tiles; each thread owns one value
    {
        float s0 = 0.f;
#pragma unroll
        for (int w2 = 0; w2 < 8; ++w2) s0 += tiles[w2 * 1024 + tid];
        // idx = (nt*4+r)*64 + lane' ; t = (lane'>>4)*4 + r ; e = nt*16 + (lane'&15)
        const int j = tid >> 6, ln = tid & 63;
        const int t = (ln >> 4) * 4 + (j & 3);
        const int e = (j >> 2) * 16 + (ln & 15);
        fin[t * 64 + e] = s0;
    }
    __syncthreads();

    // ---- per-wave top-8: wave wv handles token wv ----
    {
        const int t = wv;
        float v = fin[t * 64 + lane];
        float wj[TOPK];
        int   ij[TOPK];
        float wsum = 0.f;
#pragma unroll
        for (int j = 0; j < TOPK; ++j) {
            float mx = v;
#pragma unroll
            for (int off = 32; off >= 1; off >>= 1)
                mx = fmaxf(mx, __shfl_xor(mx, off));
            const unsigned long long msk = __ballot(v == mx);
            const int widx = (int)__builtin_ctzll(msk);   // lowest index on ties
            wj[j] = 1.f / (1.f + expf(-mx));
            ij[j] = widx;
            wsum += wj[j];
            if (lane == widx) v = -INFINITY;
        }
        const float inv = 1.f / fmaxf(wsum, 1e-12f);
        const int tg = tok0 + t;
        if (lane == 0) {
#pragma unroll
            for (int j = 0; j < TOPK; ++j)
                out[(size_t)tg * TOPK + j] = wj[j] * inv;
#pragma unroll
            for (int j = 0; j < TOPK; ++j)
                out[(size_t)T_TOTAL * TOPK + (size_t)tg * TOPK + j] = (float)ij[j];
        }
    }
}

extern "C" void kernel_launch(void* const* d_in, const int* in_sizes, int n_in,
                              void* d_out, int out_size, void* d_ws, size_t ws_size,
                              hipStream_t stream) {
    const float* x = (const float*)d_in[0];
    const float* w = (const float*)d_in[1];
    float* out = (float*)d_out;

    short8* Bh = (short8*)d_ws;
    short8* Bm = Bh + (size_t)NKB * 4 * 64;
    short8* Bl = Bm + (size_t)NKB * 4 * 64;

    prep_w<<<NKB * 4 * 64 / 256, 256, 0, stream>>>(w, Bh, Bm, Bl);
    fused_router<<<T_TOTAL / 16, 1024, 0, stream>>>(x, Bh, Bm, Bl, out);
}